// Round 15
// baseline (388.101 us; speedup 1.0000x reference)
//
#include <hip/hip_runtime.h>
#include <math.h>

typedef unsigned short u16;
typedef __bf16 bf16x8 __attribute__((ext_vector_type(8)));
typedef float f32x4 __attribute__((ext_vector_type(4)));
typedef unsigned short u16x4 __attribute__((ext_vector_type(4)));
typedef unsigned short u16x8 __attribute__((ext_vector_type(8)));

__device__ __forceinline__ u16 f2bf(float f) {
    unsigned int u = __float_as_uint(f);
    return (u16)((u + 0x7FFF + ((u >> 16) & 1)) >> 16);
}

#define BAR() do { __builtin_amdgcn_sched_barrier(0); __builtin_amdgcn_s_barrier(); __builtin_amdgcn_sched_barrier(0); } while (0)

// ===========================================================================
// Chunk map shared by both cores (r8/r13-verified: 0 bank conflicts,
// 128B-coalesced staging): 16B chunk(row,kc) stored at row*8 + (kc^(row&7));
// read idx row*8 + (ks^(row&7)) holds kc=ks -> exact MFMA lane k-map,
// bit-identical numerics.
// ===========================================================================

// ---------------------------------------------------------------------------
// gemm128: m97-regime core. 128x128 tile, BK=64, 4 waves (2x2), SINGLE 32KB
// LDS buffer, 2 __syncthreads per K-tile (compiler emits vmcnt(0) drain --
// r1/r2-proven). Small LDS + __launch_bounds__(256,4) -> 4 blocks/CU: the
// barrier drain of one block is covered by the other three (m97/m114: this
// cross-block overlap is what the 1-blk/CU 2-phase class lacks; 874 TF).
// ---------------------------------------------------------------------------
__device__ __forceinline__ void stg128(
    const u16* __restrict__ g, int ld, int row0, int rstride, int kt,
    u16* lds, int w, int l)
{
    #pragma unroll
    for (int qq = 0; qq < 4; ++qq) {
        const int c0 = qq * 256 + w * 64;        // wave-uniform chunk base
        const int c  = c0 + l;                   // 0..1023: row = c>>3 (0..127)
        const int row = c >> 3, kcs = c & 7;
        const int kc  = kcs ^ (row & 7);         // pre-swizzled global source
        const u16* src = g + (size_t)(row0 + row * rstride) * ld + kt + kc * 8;
        __builtin_amdgcn_global_load_lds(
            (const __attribute__((address_space(1))) unsigned int*)src,
            (__attribute__((address_space(3))) unsigned int*)(lds + (size_t)c0 * 8),
            16, 0, 0);
    }
}

template<int NT>
__device__ __forceinline__ void gemm128(
    const u16* __restrict__ Ag, int ldA, int baseA, int rsA,
    const u16* __restrict__ Bg, int ldB, int n0,
    u16* sm, f32x4 (&acc)[4][4])
{
    const int tid = threadIdx.x;
    const int l = tid & 63, w = tid >> 6;
    const int p = l & 15, g = l >> 4;
    const int wm = (w >> 1) * 64, wn = (w & 1) * 64;

    stg128(Ag, ldA, baseA, rsA, 0, sm, w, l);
    stg128(Bg, ldB, n0, 1, 0, sm + 8192, w, l);

    for (int t = 0; t < NT; ++t) {
        __syncthreads();                  // vmcnt(0) drain + barrier
        bf16x8 bfr[4][2];
        #pragma unroll
        for (int nf = 0; nf < 4; ++nf) {
            int row = wn + nf * 16 + p;
            bfr[nf][0] = *(const bf16x8*)(sm + 8192 + (size_t)(row * 8 + ((g) ^ (row & 7))) * 8);
            bfr[nf][1] = *(const bf16x8*)(sm + 8192 + (size_t)(row * 8 + ((4 + g) ^ (row & 7))) * 8);
        }
        bf16x8 af[4][2];
        #pragma unroll
        for (int i = 0; i < 4; ++i) {
            int row = wm + i * 16 + p;
            af[i][0] = *(const bf16x8*)(sm + (size_t)(row * 8 + ((g) ^ (row & 7))) * 8);
            af[i][1] = *(const bf16x8*)(sm + (size_t)(row * 8 + ((4 + g) ^ (row & 7))) * 8);
        }
        __builtin_amdgcn_s_setprio(1);
        #pragma unroll
        for (int i = 0; i < 4; ++i)
            #pragma unroll
            for (int nf = 0; nf < 4; ++nf) {
                acc[i][nf] = __builtin_amdgcn_mfma_f32_16x16x32_bf16(af[i][0], bfr[nf][0], acc[i][nf], 0, 0, 0);
                acc[i][nf] = __builtin_amdgcn_mfma_f32_16x16x32_bf16(af[i][1], bfr[nf][1], acc[i][nf], 0, 0, 0);
            }
        __builtin_amdgcn_s_setprio(0);
        __syncthreads();                  // all reads done before overwrite
        if (t + 1 < NT) {
            stg128(Ag, ldA, baseA, rsA, (t + 1) * 64, sm, w, l);
            stg128(Bg, ldB, n0, 1, (t + 1) * 64, sm + 8192, w, l);
        }
    }
}

// ===========================================================================
// gemm256: r13 BK=64 2-buf core (128KB LDS) -- kept for k2/k4/k5.
// ===========================================================================
__device__ __forceinline__ void stg64(
    const u16* __restrict__ g, int ld, int row0, int rstride, int kt,
    u16* lds, int w, int l)
{
    #pragma unroll
    for (int qq = 0; qq < 4; ++qq) {
        const int c0 = qq * 512 + w * 64;
        const int c  = c0 + l;                   // 0..2047: row = c>>3
        const int row = c >> 3, kcs = c & 7;
        const int kc  = kcs ^ (row & 7);
        const u16* src = g + (size_t)(row0 + row * rstride) * ld + kt + kc * 8;
        __builtin_amdgcn_global_load_lds(
            (const __attribute__((address_space(1))) unsigned int*)src,
            (__attribute__((address_space(3))) unsigned int*)(lds + (size_t)c0 * 8),
            16, 0, 0);
    }
}

template<int NT>
__device__ __forceinline__ void gemm256(
    const u16* __restrict__ Ag, int ldA, int baseA, int rsA,
    const u16* __restrict__ Bg, int ldB, int n0,
    u16* sm, f32x4 (&acc)[8][4])
{
    const int tid = threadIdx.x;
    const int l = tid & 63, w = tid >> 6;
    const int p = l & 15, g = l >> 4;
    const int wm = (w >> 2) * 128;
    const int wn = (w & 3) * 64;

    stg64(Ag, ldA, baseA, rsA, 0, sm, w, l);
    stg64(Bg, ldB, n0, 1, 0, sm + 16384, w, l);

    #pragma unroll
    for (int t = 0; t < NT; ++t) {
        u16* bufA = sm + (t & 1) * 32768;
        u16* bufB = bufA + 16384;
        u16* nbuf = sm + ((t + 1) & 1) * 32768;

        if (t + 1 < NT) {
            stg64(Ag, ldA, baseA, rsA, (t + 1) * 64, nbuf, w, l);
            asm volatile("s_waitcnt vmcnt(4)" ::: "memory");
        } else {
            asm volatile("s_waitcnt vmcnt(0)" ::: "memory");
        }
        BAR();
        bf16x8 bfr[4][2];
        #pragma unroll
        for (int nf = 0; nf < 4; ++nf) {
            int row = wn + nf * 16 + p;
            bfr[nf][0] = *(const bf16x8*)(bufB + (size_t)(row * 8 + ((g) ^ (row & 7))) * 8);
            bfr[nf][1] = *(const bf16x8*)(bufB + (size_t)(row * 8 + ((4 + g) ^ (row & 7))) * 8);
        }
        {
            bf16x8 af[4][2];
            #pragma unroll
            for (int i = 0; i < 4; ++i) {
                int row = wm + i * 16 + p;
                af[i][0] = *(const bf16x8*)(bufA + (size_t)(row * 8 + ((g) ^ (row & 7))) * 8);
                af[i][1] = *(const bf16x8*)(bufA + (size_t)(row * 8 + ((4 + g) ^ (row & 7))) * 8);
            }
            __builtin_amdgcn_s_setprio(1);
            #pragma unroll
            for (int i = 0; i < 4; ++i)
                #pragma unroll
                for (int nf = 0; nf < 4; ++nf) {
                    acc[i][nf] = __builtin_amdgcn_mfma_f32_16x16x32_bf16(af[i][0], bfr[nf][0], acc[i][nf], 0, 0, 0);
                    acc[i][nf] = __builtin_amdgcn_mfma_f32_16x16x32_bf16(af[i][1], bfr[nf][1], acc[i][nf], 0, 0, 0);
                }
            __builtin_amdgcn_s_setprio(0);
        }
        if (t + 1 < NT) stg64(Bg, ldB, n0, 1, (t + 1) * 64, nbuf + 16384, w, l);
        {
            bf16x8 af[4][2];
            #pragma unroll
            for (int i = 0; i < 4; ++i) {
                int row = wm + (4 + i) * 16 + p;
                af[i][0] = *(const bf16x8*)(bufA + (size_t)(row * 8 + ((g) ^ (row & 7))) * 8);
                af[i][1] = *(const bf16x8*)(bufA + (size_t)(row * 8 + ((4 + g) ^ (row & 7))) * 8);
            }
            __builtin_amdgcn_s_setprio(1);
            #pragma unroll
            for (int i = 0; i < 4; ++i)
                #pragma unroll
                for (int nf = 0; nf < 4; ++nf) {
                    acc[4 + i][nf] = __builtin_amdgcn_mfma_f32_16x16x32_bf16(af[i][0], bfr[nf][0], acc[4 + i][nf], 0, 0, 0);
                    acc[4 + i][nf] = __builtin_amdgcn_mfma_f32_16x16x32_bf16(af[i][1], bfr[nf][1], acc[4 + i][nf], 0, 0, 0);
                }
            __builtin_amdgcn_s_setprio(0);
        }
        BAR();
    }
}

// ---------------------------------------------------------------------------
// K0: merged prep. z<16: xT[b][n][c] (bf16) = x[b][c][n] (f32).
// z==16: weight f32->bf16 conversion (512 blocks exactly).
// ---------------------------------------------------------------------------
__global__ __launch_bounds__(256) void k0_prep(
    const float* __restrict__ x, u16* __restrict__ xT,
    const float* __restrict__ Wq, const float* __restrict__ Wk,
    const float* __restrict__ Wv, const float* __restrict__ Wo,
    u16* __restrict__ wqk, u16* __restrict__ wv, u16* __restrict__ wo)
{
    const int tid = threadIdx.x;
    if (blockIdx.z == 16) {
        const int bid = blockIdx.y * 64 + blockIdx.x;   // 0..511
        const int sel = bid >> 7;
        const int sub = bid & 127;
        const float* s = sel == 0 ? Wq : sel == 1 ? Wk : sel == 2 ? Wv : Wo;
        u16* d = sel == 0 ? wqk : sel == 1 ? (wqk + 131072) : sel == 2 ? wv : wo;
        int i = (sub * 256 + tid) * 4;
        float4 v = *(const float4*)(s + i);
        u16x4 u = {f2bf(v.x), f2bf(v.y), f2bf(v.z), f2bf(v.w)};
        *(u16x4*)(d + i) = u;
        return;
    }
    __shared__ float Tx[64 * 65];
    const int b = blockIdx.z, c0 = blockIdx.y * 64, n0 = blockIdx.x * 64;
    const float* xb = x + (size_t)b * 512 * 4096;
    #pragma unroll
    for (int r = 0; r < 4; ++r) {
        int crow = (tid >> 4) + r * 16;
        int ncol = (tid & 15) * 4;
        float4 v = *(const float4*)(xb + (size_t)(c0 + crow) * 4096 + n0 + ncol);
        Tx[(ncol + 0) * 65 + crow] = v.x;
        Tx[(ncol + 1) * 65 + crow] = v.y;
        Tx[(ncol + 2) * 65 + crow] = v.z;
        Tx[(ncol + 3) * 65 + crow] = v.w;
    }
    __syncthreads();
    u16* ob = xT + (size_t)b * 4096 * 512;
    #pragma unroll
    for (int cc = 0; cc < 2; ++cc) {
        int id = cc * 256 + tid;
        int nrow = id >> 3;
        int cch = (id & 7) * 8;
        u16x8 u;
        #pragma unroll
        for (int j = 0; j < 8; ++j) u[j] = f2bf(Tx[nrow * 65 + cch + j]);
        *(u16x8*)(ob + (size_t)(n0 + nrow) * 512 + c0 + cch) = u;
    }
}

// ---------------------------------------------------------------------------
// K1: merged q/k/v, m97-regime gemm128. grid (64, 3, 16), 256 threads,
// 4 blocks/CU. x encodes (mt = x&1, nt = x>>1) for y<2; (dt = x&1,
// st = x>>1) for y==2. Consecutive x share the same xT B-panel.
// y<2:  q,k = wqk . xT^T + bias  (m0 = y*256 + mt*128, n0 = nt*128)
// y==2: vT[n][d] = xT[n][:] . Wv[d][:] + bv[d]  (m0 = st*128, n0 = dt*128)
// ---------------------------------------------------------------------------
__global__ __launch_bounds__(256, 4) void k1_qkv(
    const u16* __restrict__ wqk, const u16* __restrict__ wv,
    const float* __restrict__ bq, const float* __restrict__ bk, const float* __restrict__ bv,
    const u16* __restrict__ xT, u16* __restrict__ q, u16* __restrict__ kmat,
    u16* __restrict__ vT)
{
    __shared__ u16 sm[16384];   // 32KB: A 16KB + B 16KB, single buffer
    const int b = blockIdx.z;
    const int y = blockIdx.y;
    const u16* xb = xT + (size_t)b * 4096 * 512;

    const int tid = threadIdx.x;
    const int l = tid & 63, w = tid >> 6;
    const int p = l & 15, g = l >> 4;
    const int wm = (w >> 1) * 64, wn = (w & 1) * 64;

    f32x4 acc[4][4] = {};

    if (y < 2) {
        const int mt = blockIdx.x & 1, nt = blockIdx.x >> 1;
        const int m0 = y * 256 + mt * 128;
        const int n0 = nt * 128;
        gemm128<8>(wqk, 512, m0, 1, xb, 512, n0, sm, acc);

        const float* bias = (y == 0) ? bq : bk;
        u16* outp = ((y == 0) ? q : kmat) + ((size_t)b << 20);
        #pragma unroll
        for (int mf = 0; mf < 4; ++mf)
            #pragma unroll
            for (int nf = 0; nf < 4; ++nf) {
                int n = n0 + wn + nf * 16 + p;
                #pragma unroll
                for (int r = 0; r < 4; ++r) {
                    int mloc = mt * 128 + wm + mf * 16 + g * 4 + r;  // 0..255
                    outp[(size_t)mloc * 4096 + n] = f2bf(acc[mf][nf][r] + bias[mloc]);
                }
            }
    } else {
        const int dt = blockIdx.x & 1, st = blockIdx.x >> 1;
        const int m0 = st * 128;
        const int n0 = dt * 128;
        gemm128<8>(xb, 512, m0, 1, wv, 512, n0, sm, acc);

        u16* outp = vT + ((size_t)b << 20);
        #pragma unroll
        for (int nf = 0; nf < 4; ++nf) {
            int d = n0 + wn + nf * 16 + p;
            float bvv = bv[d];
            #pragma unroll
            for (int mf = 0; mf < 4; ++mf) {
                #pragma unroll
                for (int r = 0; r < 4; ++r) {
                    int row = m0 + wm + mf * 16 + g * 4 + r;
                    outp[(size_t)row * 256 + d] = f2bf(acc[mf][nf][r] + bvv);
                }
            }
        }
    }
}

// ---------------------------------------------------------------------------
// K2: score partials, split-K=8 (r13). grid (8, 1, 16). K-slice split*512.
// ---------------------------------------------------------------------------
__global__ __launch_bounds__(512, 2) void k2_scores(
    const u16* __restrict__ q, const u16* __restrict__ kmat, float* __restrict__ spart)
{
    __shared__ u16 sm[65536];
    const int b = blockIdx.z;
    const int split = blockIdx.x;
    const u16* A = q    + ((size_t)b << 20) + split * 512;
    const u16* B = kmat + ((size_t)b << 20) + split * 512;

    f32x4 acc[8][4] = {};
    gemm256<8>(A, 4096, 0, 1, B, 4096, 0, sm, acc);

    const int tid = threadIdx.x;
    const int l = tid & 63, w = tid >> 6;
    const int p = l & 15, g = l >> 4;
    const int wm = (w >> 2) * 128, wn = (w & 3) * 64;

    float* sp = spart + ((size_t)split * 16 + b) * 65536;
    #pragma unroll
    for (int mf = 0; mf < 8; ++mf)
        #pragma unroll
        for (int nf = 0; nf < 4; ++nf) {
            int n = wn + nf * 16 + p;
            #pragma unroll
            for (int r = 0; r < 4; ++r) {
                int m = wm + mf * 16 + g * 4 + r;
                sp[(size_t)m * 256 + n] = acc[mf][nf][r] * 0.015625f;
            }
        }
}

// ---------------------------------------------------------------------------
// K3: reduce 8 split partials + softmax over d -> bf16 attn
// ---------------------------------------------------------------------------
__global__ __launch_bounds__(256) void k3_softmax(
    const float* __restrict__ sp, u16* __restrict__ attn)
{
    const int row = blockIdx.x;
    const int tid = threadIdx.x;
    const size_t STRIDE = (size_t)16 * 65536;
    const size_t base = (size_t)row * 256 + tid;

    float s = 0.f;
    #pragma unroll
    for (int i = 0; i < 8; ++i) s += sp[base + i * STRIDE];

    __shared__ float red[4];
    float m = s;
    #pragma unroll
    for (int off = 32; off >= 1; off >>= 1) m = fmaxf(m, __shfl_xor(m, off));
    if ((tid & 63) == 0) red[tid >> 6] = m;
    __syncthreads();
    m = fmaxf(fmaxf(red[0], red[1]), fmaxf(red[2], red[3]));

    float e = expf(s - m);
    float t = e;
    #pragma unroll
    for (int off = 32; off >= 1; off >>= 1) t += __shfl_xor(t, off);
    __syncthreads();
    if ((tid & 63) == 0) red[tid >> 6] = t;
    __syncthreads();
    t = red[0] + red[1] + red[2] + red[3];

    attn[base] = f2bf(e / t);
}

// ---------------------------------------------------------------------------
// K4: outT3[b][sh][co][nh] = sum_d attn[b][co][d] * vT[b][16nh+sh][d]
// Per (b,sh): M=256 (nh via rstride-16 A rows), N=256 (co), K=256, NT=4.
// grid (16=sh, 1, 16=b), 512 threads.
// ---------------------------------------------------------------------------
__global__ __launch_bounds__(512, 2) void k4_pv(
    const u16* __restrict__ attn, const u16* __restrict__ vT, u16* __restrict__ outT3)
{
    __shared__ u16 sm[65536];
    const int b  = blockIdx.z;
    const int sh = blockIdx.x;
    const u16* A = vT   + ((size_t)b << 20);   // rows 16m+sh
    const u16* B = attn + ((size_t)b << 16);

    f32x4 acc[8][4] = {};
    gemm256<4>(A, 256, sh, 16, B, 256, 0, sm, acc);

    const int tid = threadIdx.x;
    const int l = tid & 63, w = tid >> 6;
    const int p = l & 15, g = l >> 4;
    const int wm = (w >> 2) * 128, wn = (w & 3) * 64;

    u16* outp = outT3 + (((size_t)b * 16 + sh) << 16);
    #pragma unroll
    for (int mf = 0; mf < 8; ++mf)
        #pragma unroll
        for (int nf = 0; nf < 4; ++nf) {
            int co  = wn + nf * 16 + p;
            int nh0 = wm + mf * 16 + g * 4;
            u16x4 u = {f2bf(acc[mf][nf][0]), f2bf(acc[mf][nf][1]),
                       f2bf(acc[mf][nf][2]), f2bf(acc[mf][nf][3])};
            *(u16x4*)(outp + (size_t)co * 256 + nh0) = u;
        }
}

// ---------------------------------------------------------------------------
// K5: final[b][c][sh*256+slo] = sum_nh Wo[c][nh] * outT3[b][sh][slo][nh] + bo[c]
// Per (b,sh): M=512 (c), N=256 (slo), K=256, NT=4. grid (1, 2, 256).
// ---------------------------------------------------------------------------
__global__ __launch_bounds__(512, 2) void k5_final(
    const u16* __restrict__ wo, const float* __restrict__ bo,
    const u16* __restrict__ outT3, float* __restrict__ out)
{
    __shared__ u16 sm[65536];
    const int bz = blockIdx.z;               // b*16 + sh
    const int b  = bz >> 4, sh = bz & 15;
    const int m0 = blockIdx.y * 256;
    const u16* B = outT3 + ((size_t)bz << 16);

    f32x4 acc[8][4] = {};
    gemm256<4>(wo, 256, m0, 1, B, 256, 0, sm, acc);

    const int tid = threadIdx.x;
    const int l = tid & 63, w = tid >> 6;
    const int p = l & 15, g = l >> 4;
    const int wm = (w >> 2) * 128, wn = (w & 3) * 64;

    float* ob = out + (size_t)b * 2097152 + (size_t)sh * 256;
    #pragma unroll
    for (int mf = 0; mf < 8; ++mf)
        #pragma unroll
        for (int nf = 0; nf < 4; ++nf) {
            int slo = wn + nf * 16 + p;
            #pragma unroll
            for (int r = 0; r < 4; ++r) {
                int m = m0 + wm + mf * 16 + g * 4 + r;
                ob[(size_t)m * 4096 + slo] = acc[mf][nf][r] + bo[m];
            }
        }
}

// ---------------------------------------------------------------------------
extern "C" void kernel_launch(void* const* d_in, const int* in_sizes, int n_in,
                              void* d_out, int out_size, void* d_ws, size_t ws_size,
                              hipStream_t stream) {
    (void)in_sizes; (void)n_in; (void)out_size; (void)ws_size;
    const float* x  = (const float*)d_in[0];
    const float* Wq = (const float*)d_in[1];
    const float* bq = (const float*)d_in[2];
    const float* Wk = (const float*)d_in[3];
    const float* bk = (const float*)d_in[4];
    const float* Wv = (const float*)d_in[5];
    const float* bv = (const float*)d_in[6];
    const float* Wo = (const float*)d_in[7];
    const float* bo = (const float*)d_in[8];
    float* out = (float*)d_out;

    char* ws = (char*)d_ws;
    u16* xT   = (u16*)(ws + 0);             // 67.1MB, dead after k1
    u16* q    = (u16*)(ws + 67108864);      // 33.5MB, dead after k2
    u16* kmat = (u16*)(ws + 100663296);     // 33.5MB, dead after k2
    u16* vT   = (u16*)(ws + 134217728);     // 33.5MB, dead after k4
    float* spart = (float*)(ws + 0);        // 33.5MB f32 (8 splits), aliases xT
    u16* attn    = (u16*)(ws + 67108864);   // 2MB, aliases q
    u16* outT3   = (u16*)(ws + 100663296);  // 33.5MB, aliases kmat
    u16* wqk  = (u16*)(ws + 167772160);     // 512KB [512][512] (q rows then k rows)
    u16* wv   = (u16*)(ws + 168296448);     // 256KB [256][512]
    u16* wo   = (u16*)(ws + 168558592);     // 256KB [512][256]

    k0_prep   <<<dim3(64, 8, 17), dim3(256), 0, stream>>>(x, xT, Wq, Wk, Wv, Wo, wqk, wv, wo);
    k1_qkv    <<<dim3(64, 3, 16), dim3(256), 0, stream>>>(wqk, wv, bq, bk, bv, xT, q, kmat, vT);
    k2_scores <<<dim3(8, 1, 16),  dim3(512), 0, stream>>>(q, kmat, spart);
    k3_softmax<<<dim3(4096),      dim3(256), 0, stream>>>(spart, attn);
    k4_pv     <<<dim3(16, 1, 16), dim3(512), 0, stream>>>(attn, vT, outT3);
    k5_final  <<<dim3(1, 2, 256), dim3(512), 0, stream>>>(wo, bo, outT3, out);
}

// Round 16
// 196.454 us; speedup vs baseline: 1.9755x; 1.9755x over previous
//
#include <hip/hip_runtime.h>
#include <math.h>

typedef unsigned short u16;
typedef __bf16 bf16x8 __attribute__((ext_vector_type(8)));
typedef float f32x4 __attribute__((ext_vector_type(4)));
typedef unsigned short u16x4 __attribute__((ext_vector_type(4)));
typedef unsigned short u16x8 __attribute__((ext_vector_type(8)));

__device__ __forceinline__ u16 f2bf(float f) {
    unsigned int u = __float_as_uint(f);
    return (u16)((u + 0x7FFF + ((u >> 16) & 1)) >> 16);
}

#define BAR() do { __builtin_amdgcn_sched_barrier(0); __builtin_amdgcn_s_barrier(); __builtin_amdgcn_sched_barrier(0); } while (0)

// ===========================================================================
// 256x256 8-wave GEMM core, BK=32, 4-deep LDS pipeline (prefetch 3 K-tiles).
// (r8 core, verified best: 0 bank conflicts, coalesced staging, 196us total.)
// A: logical row m -> global row baseA + m*rsA, k-contig (ldA).
// B: logical row n -> global row n0 + n, k-contig (ldB).
// LDS = 4 bufs x (A 16KB + B 16KB) = 128KB. 2 phases per K-tile, 16 MFMA each.
//
// LDS chunk map (16B chunks): chunk(row, kc) stored at  row*4 + (kc ^ f(row)),
// f(row) = (row>>1)&3.  Staging: 16 x 64B coalesced requests per instr.
// Reads: quarter-wave lane p -> bank group 4(p&1) + (g ^ ((p>>1)&3)) ->
// 2 lanes/bank = free (m136). Content: read index row*4+(g^f) holds kc=g.
//
// Counted waits: at gate of tile t, instrs newer than B(t) are A/B(t+1),
// A/B(t+2), A(t+3) = 10 (steady); tail r=NT-1-t: 2->8, 1->4, 0->0.
// Buffer reuse: stg(t+3) -> buf (t-1)&3, issued after end-of-(t-1) barrier.
//
// Regime ledger (r5-r15): this 256^2/1-blk-CU family is traffic-OPTIMAL
// (FETCH 47MB); small-tile/high-occupancy regimes blow up fetch 12x (r15)
// or writes 3x (r9); dispatch reorder blows fetch 2.3x (r11). Nine k1
// schedule variants all land 90-100us = the 2-phase class ceiling.
// ===========================================================================
__device__ __forceinline__ void stg(
    const u16* __restrict__ g, int ld, int row0, int rstride, int kt,
    u16* lds, int w, int l)
{
    #pragma unroll
    for (int qq = 0; qq < 2; ++qq) {
        const int c0 = qq * 512 + w * 64;        // wave-uniform chunk base
        const int c  = c0 + l;                   // chunk: row = c>>2, kcs = c&3
        const int row = c >> 2, kcs = c & 3;
        const int kc  = kcs ^ ((row >> 1) & 3);  // pre-swizzled global source
        const u16* src = g + (size_t)(row0 + row * rstride) * ld + kt + kc * 8;
        __builtin_amdgcn_global_load_lds(
            (const __attribute__((address_space(1))) unsigned int*)src,
            (__attribute__((address_space(3))) unsigned int*)(lds + (size_t)c0 * 8),
            16, 0, 0);
    }
}

template<int NT>
__device__ __forceinline__ void gemm256(
    const u16* __restrict__ Ag, int ldA, int baseA, int rsA,
    const u16* __restrict__ Bg, int ldB, int n0,
    u16* sm, f32x4 (&acc)[8][4])
{
    const int tid = threadIdx.x;
    const int l = tid & 63, w = tid >> 6;
    const int p = l & 15, g = l >> 4;
    const int wm = (w >> 2) * 128;   // 2 M-waves
    const int wn = (w & 3) * 64;     // 4 N-waves

    // prologue: stage tiles 0..2 (12 load-instrs/wave outstanding)
    #pragma unroll
    for (int t = 0; t < 3; ++t) {
        u16* buf = sm + (t & 3) * 16384;
        stg(Ag, ldA, baseA, rsA, t * 32, buf, w, l);
        stg(Bg, ldB, n0, 1, t * 32, buf + 8192, w, l);
    }

    #pragma unroll
    for (int t = 0; t < NT; ++t) {
        u16* bufA = sm + (t & 3) * 16384;
        u16* bufB = bufA + 8192;
        u16* nbuf = sm + ((t + 3) & 3) * 16384;

        // ---- phase 1: stage A(t+3); counted gate for tile t; half 1 ----
        if (t + 3 < NT) stg(Ag, ldA, baseA, rsA, (t + 3) * 32, nbuf, w, l);
        {
            const int r = NT - 1 - t;
            if (r >= 3)      asm volatile("s_waitcnt vmcnt(10)" ::: "memory");
            else if (r == 2) asm volatile("s_waitcnt vmcnt(8)"  ::: "memory");
            else if (r == 1) asm volatile("s_waitcnt vmcnt(4)"  ::: "memory");
            else             asm volatile("s_waitcnt vmcnt(0)"  ::: "memory");
        }
        BAR();
        bf16x8 bfr[4];
        #pragma unroll
        for (int nf = 0; nf < 4; ++nf) {
            int row = wn + nf * 16 + p;
            bfr[nf] = *(const bf16x8*)(bufB + (size_t)(row * 4 + (g ^ ((row >> 1) & 3))) * 8);
        }
        {
            bf16x8 af[4];
            #pragma unroll
            for (int i = 0; i < 4; ++i) {
                int row = wm + i * 16 + p;
                af[i] = *(const bf16x8*)(bufA + (size_t)(row * 4 + (g ^ ((row >> 1) & 3))) * 8);
            }
            __builtin_amdgcn_s_setprio(1);
            #pragma unroll
            for (int i = 0; i < 4; ++i)
                #pragma unroll
                for (int nf = 0; nf < 4; ++nf)
                    acc[i][nf] = __builtin_amdgcn_mfma_f32_16x16x32_bf16(af[i], bfr[nf], acc[i][nf], 0, 0, 0);
            __builtin_amdgcn_s_setprio(0);
        }
        // ---- phase 2: stage B(t+3); half 2 ----
        if (t + 3 < NT) stg(Bg, ldB, n0, 1, (t + 3) * 32, nbuf + 8192, w, l);
        {
            bf16x8 af[4];
            #pragma unroll
            for (int i = 0; i < 4; ++i) {
                int row = wm + (4 + i) * 16 + p;
                af[i] = *(const bf16x8*)(bufA + (size_t)(row * 4 + (g ^ ((row >> 1) & 3))) * 8);
            }
            __builtin_amdgcn_s_setprio(1);
            #pragma unroll
            for (int i = 0; i < 4; ++i)
                #pragma unroll
                for (int nf = 0; nf < 4; ++nf)
                    acc[4 + i][nf] = __builtin_amdgcn_mfma_f32_16x16x32_bf16(af[i], bfr[nf], acc[4 + i][nf], 0, 0, 0);
            __builtin_amdgcn_s_setprio(0);
        }
        BAR();
    }
}

// ---------------------------------------------------------------------------
// K0: merged prep. z<16: xT[b][n][c] (bf16) = x[b][c][n] (f32).
// z==16: weight f32->bf16 conversion (512 blocks exactly).
// ---------------------------------------------------------------------------
__global__ __launch_bounds__(256) void k0_prep(
    const float* __restrict__ x, u16* __restrict__ xT,
    const float* __restrict__ Wq, const float* __restrict__ Wk,
    const float* __restrict__ Wv, const float* __restrict__ Wo,
    u16* __restrict__ wqk, u16* __restrict__ wv, u16* __restrict__ wo)
{
    const int tid = threadIdx.x;
    if (blockIdx.z == 16) {
        const int bid = blockIdx.y * 64 + blockIdx.x;   // 0..511
        const int sel = bid >> 7;
        const int sub = bid & 127;
        const float* s = sel == 0 ? Wq : sel == 1 ? Wk : sel == 2 ? Wv : Wo;
        u16* d = sel == 0 ? wqk : sel == 1 ? (wqk + 131072) : sel == 2 ? wv : wo;
        int i = (sub * 256 + tid) * 4;
        float4 v = *(const float4*)(s + i);
        u16x4 u = {f2bf(v.x), f2bf(v.y), f2bf(v.z), f2bf(v.w)};
        *(u16x4*)(d + i) = u;
        return;
    }
    __shared__ float Tx[64 * 65];
    const int b = blockIdx.z, c0 = blockIdx.y * 64, n0 = blockIdx.x * 64;
    const float* xb = x + (size_t)b * 512 * 4096;
    #pragma unroll
    for (int r = 0; r < 4; ++r) {
        int crow = (tid >> 4) + r * 16;
        int ncol = (tid & 15) * 4;
        float4 v = *(const float4*)(xb + (size_t)(c0 + crow) * 4096 + n0 + ncol);
        Tx[(ncol + 0) * 65 + crow] = v.x;
        Tx[(ncol + 1) * 65 + crow] = v.y;
        Tx[(ncol + 2) * 65 + crow] = v.z;
        Tx[(ncol + 3) * 65 + crow] = v.w;
    }
    __syncthreads();
    u16* ob = xT + (size_t)b * 4096 * 512;
    #pragma unroll
    for (int cc = 0; cc < 2; ++cc) {
        int id = cc * 256 + tid;
        int nrow = id >> 3;
        int cch = (id & 7) * 8;
        u16x8 u;
        #pragma unroll
        for (int j = 0; j < 8; ++j) u[j] = f2bf(Tx[nrow * 65 + cch + j]);
        *(u16x8*)(ob + (size_t)(n0 + nrow) * 512 + c0 + cch) = u;
    }
}

// ---------------------------------------------------------------------------
// K1: merged q/k/v. grid (16, 3, 16): the three y-variants of one (tile,b)
// sit at flat-id stride 16 == 0 mod 8 -> SAME XCD -> shared xT panel in L2.
// y<2:  q,k = wqk . xT^T + bias  (m0 = y*256, n0 = x*256)
// y==2: vT[n][d] = xT[n][:] . Wv[d][:] + bv[d]  (m0 = x*256 over spatial)
// ---------------------------------------------------------------------------
__global__ __launch_bounds__(512, 2) void k1_qkv(
    const u16* __restrict__ wqk, const u16* __restrict__ wv,
    const float* __restrict__ bq, const float* __restrict__ bk, const float* __restrict__ bv,
    const u16* __restrict__ xT, u16* __restrict__ q, u16* __restrict__ kmat,
    u16* __restrict__ vT)
{
    __shared__ u16 sm[65536];
    const int b = blockIdx.z;
    const int y = blockIdx.y;
    const int tile = blockIdx.x;         // 0..15
    const u16* xb = xT + (size_t)b * 4096 * 512;

    const int tid = threadIdx.x;
    const int l = tid & 63, w = tid >> 6;
    const int p = l & 15, g = l >> 4;
    const int wm = (w >> 2) * 128, wn = (w & 3) * 64;

    f32x4 acc[8][4] = {};

    if (y < 2) {
        const int m0 = y * 256;
        const int n0 = tile * 256;
        gemm256<16>(wqk, 512, m0, 1, xb, 512, n0, sm, acc);

        const float* bias = (y == 0) ? bq : bk;
        u16* outp = ((y == 0) ? q : kmat) + ((size_t)b << 20);
        #pragma unroll
        for (int mf = 0; mf < 8; ++mf)
            #pragma unroll
            for (int nf = 0; nf < 4; ++nf) {
                int n = n0 + wn + nf * 16 + p;
                #pragma unroll
                for (int r = 0; r < 4; ++r) {
                    int mloc = wm + mf * 16 + g * 4 + r;
                    outp[(size_t)mloc * 4096 + n] = f2bf(acc[mf][nf][r] + bias[mloc]);
                }
            }
    } else {
        const int m0 = tile * 256;
        gemm256<16>(xb, 512, m0, 1, wv, 512, 0, sm, acc);

        u16* outp = vT + ((size_t)b << 20);
        #pragma unroll
        for (int nf = 0; nf < 4; ++nf) {
            int d = wn + nf * 16 + p;
            float bvv = bv[d];
            #pragma unroll
            for (int mf = 0; mf < 8; ++mf) {
                #pragma unroll
                for (int r = 0; r < 4; ++r) {
                    int row = m0 + wm + mf * 16 + g * 4 + r;
                    outp[(size_t)row * 256 + d] = f2bf(acc[mf][nf][r] + bvv);
                }
            }
        }
    }
}

// ---------------------------------------------------------------------------
// K2: score partials, split-K=8. grid (8=split, 1, 16=b), 512 threads.
// K-slice = split*512 (pointer offset), NT=16.
// ---------------------------------------------------------------------------
__global__ __launch_bounds__(512, 2) void k2_scores(
    const u16* __restrict__ q, const u16* __restrict__ kmat, float* __restrict__ spart)
{
    __shared__ u16 sm[65536];
    const int b = blockIdx.z;
    const int split = blockIdx.x;
    const u16* A = q    + ((size_t)b << 20) + split * 512;
    const u16* B = kmat + ((size_t)b << 20) + split * 512;

    f32x4 acc[8][4] = {};
    gemm256<16>(A, 4096, 0, 1, B, 4096, 0, sm, acc);

    const int tid = threadIdx.x;
    const int l = tid & 63, w = tid >> 6;
    const int p = l & 15, g = l >> 4;
    const int wm = (w >> 2) * 128, wn = (w & 3) * 64;

    float* sp = spart + ((size_t)split * 16 + b) * 65536;
    #pragma unroll
    for (int mf = 0; mf < 8; ++mf)
        #pragma unroll
        for (int nf = 0; nf < 4; ++nf) {
            int n = wn + nf * 16 + p;
            #pragma unroll
            for (int r = 0; r < 4; ++r) {
                int m = wm + mf * 16 + g * 4 + r;
                sp[(size_t)m * 256 + n] = acc[mf][nf][r] * 0.015625f;
            }
        }
}

// ---------------------------------------------------------------------------
// K3: reduce 8 split partials + softmax over d -> bf16 attn
// ---------------------------------------------------------------------------
__global__ __launch_bounds__(256) void k3_softmax(
    const float* __restrict__ sp, u16* __restrict__ attn)
{
    const int row = blockIdx.x;
    const int tid = threadIdx.x;
    const size_t STRIDE = (size_t)16 * 65536;
    const size_t base = (size_t)row * 256 + tid;

    float s = 0.f;
    #pragma unroll
    for (int i = 0; i < 8; ++i) s += sp[base + i * STRIDE];

    __shared__ float red[4];
    float m = s;
    #pragma unroll
    for (int off = 32; off >= 1; off >>= 1) m = fmaxf(m, __shfl_xor(m, off));
    if ((tid & 63) == 0) red[tid >> 6] = m;
    __syncthreads();
    m = fmaxf(fmaxf(red[0], red[1]), fmaxf(red[2], red[3]));

    float e = expf(s - m);
    float t = e;
    #pragma unroll
    for (int off = 32; off >= 1; off >>= 1) t += __shfl_xor(t, off);
    __syncthreads();
    if ((tid & 63) == 0) red[tid >> 6] = t;
    __syncthreads();
    t = red[0] + red[1] + red[2] + red[3];

    attn[base] = f2bf(e / t);
}

// ---------------------------------------------------------------------------
// K4: outT3[b][sh][co][nh] = sum_d attn[b][co][d] * vT[b][16nh+sh][d]
// Per (b,sh): M=256 (nh via rstride-16 A rows), N=256 (co), K=256 (d), NT=8.
// grid (16=sh, 1, 16=b), 512 threads.
// ---------------------------------------------------------------------------
__global__ __launch_bounds__(512, 2) void k4_pv(
    const u16* __restrict__ attn, const u16* __restrict__ vT, u16* __restrict__ outT3)
{
    __shared__ u16 sm[65536];
    const int b  = blockIdx.z;
    const int sh = blockIdx.x;
    const u16* A = vT   + ((size_t)b << 20);   // rows 16m+sh
    const u16* B = attn + ((size_t)b << 16);

    f32x4 acc[8][4] = {};
    gemm256<8>(A, 256, sh, 16, B, 256, 0, sm, acc);

    const int tid = threadIdx.x;
    const int l = tid & 63, w = tid >> 6;
    const int p = l & 15, g = l >> 4;
    const int wm = (w >> 2) * 128, wn = (w & 3) * 64;

    u16* outp = outT3 + (((size_t)b * 16 + sh) << 16);
    #pragma unroll
    for (int mf = 0; mf < 8; ++mf)
        #pragma unroll
        for (int nf = 0; nf < 4; ++nf) {
            int co  = wn + nf * 16 + p;
            int nh0 = wm + mf * 16 + g * 4;
            u16x4 u = {f2bf(acc[mf][nf][0]), f2bf(acc[mf][nf][1]),
                       f2bf(acc[mf][nf][2]), f2bf(acc[mf][nf][3])};
            *(u16x4*)(outp + (size_t)co * 256 + nh0) = u;
        }
}

// ---------------------------------------------------------------------------
// K5: final[b][c][sh*256+slo] = sum_nh Wo[c][nh] * outT3[b][sh][slo][nh] + bo[c]
// Per (b,sh): M=512 (c), N=256 (slo), K=256 (nh), NT=8. grid (1, 2, 256).
// ---------------------------------------------------------------------------
__global__ __launch_bounds__(512, 2) void k5_final(
    const u16* __restrict__ wo, const float* __restrict__ bo,
    const u16* __restrict__ outT3, float* __restrict__ out)
{
    __shared__ u16 sm[65536];
    const int bz = blockIdx.z;               // b*16 + sh
    const int b  = bz >> 4, sh = bz & 15;
    const int m0 = blockIdx.y * 256;
    const u16* B = outT3 + ((size_t)bz << 16);

    f32x4 acc[8][4] = {};
    gemm256<8>(wo, 256, m0, 1, B, 256, 0, sm, acc);

    const int tid = threadIdx.x;
    const int l = tid & 63, w = tid >> 6;
    const int p = l & 15, g = l >> 4;
    const int wm = (w >> 2) * 128, wn = (w & 3) * 64;

    float* ob = out + (size_t)b * 2097152 + (size_t)sh * 256;
    #pragma unroll
    for (int mf = 0; mf < 8; ++mf)
        #pragma unroll
        for (int nf = 0; nf < 4; ++nf) {
            int slo = wn + nf * 16 + p;
            #pragma unroll
            for (int r = 0; r < 4; ++r) {
                int m = m0 + wm + mf * 16 + g * 4 + r;
                ob[(size_t)m * 4096 + slo] = acc[mf][nf][r] + bo[m];
            }
        }
}

// ---------------------------------------------------------------------------
extern "C" void kernel_launch(void* const* d_in, const int* in_sizes, int n_in,
                              void* d_out, int out_size, void* d_ws, size_t ws_size,
                              hipStream_t stream) {
    (void)in_sizes; (void)n_in; (void)out_size; (void)ws_size;
    const float* x  = (const float*)d_in[0];
    const float* Wq = (const float*)d_in[1];
    const float* bq = (const float*)d_in[2];
    const float* Wk = (const float*)d_in[3];
    const float* bk = (const float*)d_in[4];
    const float* Wv = (const float*)d_in[5];
    const float* bv = (const float*)d_in[6];
    const float* Wo = (const float*)d_in[7];
    const float* bo = (const float*)d_in[8];
    float* out = (float*)d_out;

    char* ws = (char*)d_ws;
    u16* xT   = (u16*)(ws + 0);             // 67.1MB, dead after k1
    u16* q    = (u16*)(ws + 67108864);      // 33.5MB, dead after k2
    u16* kmat = (u16*)(ws + 100663296);     // 33.5MB, dead after k2
    u16* vT   = (u16*)(ws + 134217728);     // 33.5MB, dead after k4
    float* spart = (float*)(ws + 0);        // 33.5MB f32 (8 splits), aliases xT
    u16* attn    = (u16*)(ws + 67108864);   // 2MB, aliases q
    u16* outT3   = (u16*)(ws + 100663296);  // 33.5MB, aliases kmat
    u16* wqk  = (u16*)(ws + 167772160);     // 512KB [512][512] (q rows then k rows)
    u16* wv   = (u16*)(ws + 168296448);     // 256KB [256][512]
    u16* wo   = (u16*)(ws + 168558592);     // 256KB [512][256]

    k0_prep   <<<dim3(64, 8, 17), dim3(256), 0, stream>>>(x, xT, Wq, Wk, Wv, Wo, wqk, wv, wo);
    k1_qkv    <<<dim3(16, 3, 16), dim3(512), 0, stream>>>(wqk, wv, bq, bk, bv, xT, q, kmat, vT);
    k2_scores <<<dim3(8, 1, 16),  dim3(512), 0, stream>>>(q, kmat, spart);
    k3_softmax<<<dim3(4096),      dim3(256), 0, stream>>>(spart, attn);
    k4_pv     <<<dim3(16, 1, 16), dim3(512), 0, stream>>>(attn, vT, outT3);
    k5_final  <<<dim3(1, 2, 256), dim3(512), 0, stream>>>(wo, bo, outT3, out);
}